// Round 2
// baseline (571.563 us; speedup 1.0000x reference)
//
#include <hip/hip_runtime.h>
#include <hip/hip_bf16.h>
#include <cstddef>

#define NB_NODES 44800   // B*L
#define NDOCS 128
#define DLEN 350
#define DIM 768
#define HID 256
#define NCLS 20
#define NHEADS 8

typedef __bf16 v8bf __attribute__((ext_vector_type(8)));
typedef float v4f __attribute__((ext_vector_type(4)));
using bf16 = __hip_bfloat16;

// ---- W1 [768,256] f32 -> W1T [256,768] bf16 so B-fragments are contiguous 16B loads
__global__ __launch_bounds__(256) void k_transpose(const float* __restrict__ W1,
                                                   __bf16* __restrict__ W1T) {
  int idx = blockIdx.x * 256 + threadIdx.x;   // idx = n*768 + k
  int n = idx / 768, k = idx - n * 768;
  W1T[idx] = (__bf16)W1[k * 256 + n];
}

// ---- fused gather + GEMM1(relu) + GEMM2 -> h0 [N,20] f32
// block: 16 nodes (m) x 256 hidden (n). 4 waves, each wave 16x64 via 4 MFMA frags.
__global__ __launch_bounds__(256) void k_mlp(
    const int* __restrict__ node_ids, const float* __restrict__ emb,
    const __bf16* __restrict__ W1T, const float* __restrict__ b1,
    const float* __restrict__ W2, const float* __restrict__ b2,
    float* __restrict__ h0) {
  __shared__ float xs[16 * 257];      // +1 pad: GEMM2 reads stride-257
  __shared__ float w2s[HID * NCLS];   // 20 KB
  int tid = threadIdx.x;
  int wave = tid >> 6, lane = tid & 63;
  int quad = lane >> 4, l16 = lane & 15;
  int m0 = blockIdx.x * 16;

  for (int i = tid; i < HID * NCLS; i += 256) w2s[i] = W2[i];

  int nid = node_ids[m0 + l16];
  const float* arow = emb + (size_t)nid * DIM + quad * 8;   // A: m=l16, k=quad*8+j
  const __bf16* brow = W1T + (size_t)(wave * 64 + l16) * DIM + quad * 8;

  v4f acc[4];
#pragma unroll
  for (int j = 0; j < 4; ++j) acc[j] = (v4f){0.f, 0.f, 0.f, 0.f};

  for (int k = 0; k < DIM; k += 32) {
    v4f a0 = *reinterpret_cast<const v4f*>(arow + k);
    v4f a1 = *reinterpret_cast<const v4f*>(arow + k + 4);
    v8bf a;
#pragma unroll
    for (int j = 0; j < 4; ++j) { a[j] = (__bf16)a0[j]; a[4 + j] = (__bf16)a1[j]; }
#pragma unroll
    for (int j = 0; j < 4; ++j) {
      v8bf b = *reinterpret_cast<const v8bf*>(brow + k + j * 16 * DIM);
      acc[j] = __builtin_amdgcn_mfma_f32_16x16x32_bf16(a, b, acc[j], 0, 0, 0);
    }
  }

  // epilogue: bias + relu into LDS. C/D layout: col = lane&15, row = quad*4+reg
#pragma unroll
  for (int j = 0; j < 4; ++j) {
    int n = wave * 64 + j * 16 + l16;
    float bb = b1[n];
#pragma unroll
    for (int r = 0; r < 4; ++r) {
      int m = quad * 4 + r;
      float v = acc[j][r] + bb;
      xs[m * 257 + n] = v > 0.f ? v : 0.f;
    }
  }
  __syncthreads();

  // GEMM2: [16 x 256] @ [256 x 20] + b2
  for (int idx = tid; idx < 16 * NCLS; idx += 256) {
    int m = idx / NCLS, c = idx - m * NCLS;
    float s = b2[c];
    for (int k2 = 0; k2 < HID; ++k2) s += xs[m * 257 + k2] * w2s[k2 * NCLS + c];
    h0[(size_t)(m0 + m) * NCLS + c] = s;
  }
}

// ---- per (head, node): z = h @ W[l,h], alpha_src/dst scalars
__global__ __launch_bounds__(256) void k_gat_pre(
    const float* __restrict__ hin, const float* __restrict__ gatW,
    const float* __restrict__ a_src, const float* __restrict__ a_dst, int layer,
    float* __restrict__ z, float* __restrict__ asv, float* __restrict__ adv) {
  int idx = blockIdx.x * 256 + threadIdx.x;    // < 8*N; N%256==0 so h uniform/block
  int h = idx / NB_NODES, n = idx - h * NB_NODES;
  float hi[NCLS];
#pragma unroll
  for (int c = 0; c < NCLS; ++c) hi[c] = hin[(size_t)n * NCLS + c];
  const float* W = gatW + (size_t)(layer * NHEADS + h) * NCLS * NCLS;
  const float* As = a_src + (layer * NHEADS + h) * NCLS;
  const float* Ad = a_dst + (layer * NHEADS + h) * NCLS;
  float sa = 0.f, sd = 0.f;
  size_t zb = ((size_t)h * NB_NODES + n) * NCLS;
#pragma unroll
  for (int d = 0; d < NCLS; ++d) {
    float s = 0.f;
#pragma unroll
    for (int c = 0; c < NCLS; ++c) s += hi[c] * W[c * NCLS + d];
    z[zb + d] = s;
    sa += s * As[d];
    sd += s * Ad[d];
  }
  asv[h * NB_NODES + n] = sa;
  adv[h * NB_NODES + n] = sd;
}

// ---- banded edge softmax: 7 in-neighbor slots per (head, node=dst)
__global__ __launch_bounds__(256) void k_att(
    const float* __restrict__ asv, const float* __restrict__ adv,
    float* __restrict__ att) {
  int idx = blockIdx.x * 256 + threadIdx.x;    // idx = h*N + n
  int h = idx / NB_NODES, n = idx - h * NB_NODES;
  int doc0 = (n / DLEN) * DLEN;
  float ad = adv[idx];
  float e[7];
  float m = -1e30f;
#pragma unroll
  for (int j = 0; j < 7; ++j) {
    int s = n - 3 + j;                         // src node
    bool valid = (s >= doc0) && (s < doc0 + DLEN);
    float x = valid ? asv[h * NB_NODES + s] + ad : -1e30f;
    x = x > 0.f ? x : 0.2f * x;                // leaky_relu 0.2
    e[j] = valid ? x : -1e30f;
    if (e[j] > m) m = e[j];
  }
  float sum = 0.f;
#pragma unroll
  for (int j = 0; j < 7; ++j) {
    float ex = (e[j] > -1e29f) ? expf(e[j] - m) : 0.f;
    e[j] = ex; sum += ex;
  }
  float inv = 1.f / (sum + 1e-9f);
  size_t ab = (size_t)idx * 8;
#pragma unroll
  for (int j = 0; j < 7; ++j) att[ab + j] = e[j] * inv;   // slot 7 unused
}

// ---- fused K=3 attention diffusion per (doc, head) block, elu on write
__global__ __launch_bounds__(256) void k_diffuse(
    const float* __restrict__ z, const float* __restrict__ att,
    float* __restrict__ eluzt) {
  __shared__ float zts[DLEN * NCLS];   // 7000 f32
  __shared__ float attsh[DLEN * 7];    // 2450 f32
  int tid = threadIdx.x;
  int h = blockIdx.x & 7;
  int doc = blockIdx.x >> 3;
  size_t baseN = (size_t)h * NB_NODES + (size_t)doc * DLEN;
  const float* zg = z + baseN * NCLS;
  float z0r[28], vr[28];
#pragma unroll
  for (int i = 0; i < 28; ++i) {
    int idx = tid + i * 256;
    if (idx < DLEN * NCLS) { float v = zg[idx]; zts[idx] = v; z0r[i] = v; }
  }
  for (int i = tid; i < DLEN * 7; i += 256) {
    int n = i / 7, s2 = i - n * 7;
    attsh[i] = att[(baseN + n) * 8 + s2];
  }
  __syncthreads();
  for (int t = 0; t < 3; ++t) {
#pragma unroll
    for (int i = 0; i < 28; ++i) {
      int idx = tid + i * 256;
      if (idx < DLEN * NCLS) {
        int n = idx / NCLS, c = idx - n * NCLS;
        float agg = 0.f;
#pragma unroll
        for (int j = 0; j < 7; ++j) {
          int s = n - 3 + j;
          s = s < 0 ? 0 : (s > DLEN - 1 ? DLEN - 1 : s);  // invalid slots have att 0
          agg += attsh[n * 7 + j] * zts[s * NCLS + c];
        }
        vr[i] = 0.85f * agg + 0.15f * z0r[i];
      }
    }
    __syncthreads();
#pragma unroll
    for (int i = 0; i < 28; ++i) {
      int idx = tid + i * 256;
      if (idx < DLEN * NCLS) zts[idx] = vr[i];
    }
    __syncthreads();
  }
  float* og = eluzt + baseN * NCLS;
#pragma unroll
  for (int i = 0; i < 28; ++i) {
    int idx = tid + i * 256;
    if (idx < DLEN * NCLS) {
      float x = vr[i];
      og[idx] = x > 0.f ? x : expf(x) - 1.f;   // elu
    }
  }
}

// ---- mean over heads
__global__ __launch_bounds__(256) void k_headmean(
    const float* __restrict__ eluzt, float* __restrict__ hout) {
  size_t idx = (size_t)blockIdx.x * 256 + threadIdx.x;   // < N*20
  float s = 0.f;
#pragma unroll
  for (int h = 0; h < NHEADS; ++h)
    s += eluzt[(size_t)h * NB_NODES * NCLS + idx];
  hout[idx] = 0.125f * s;
}

// ---- gated pooling per doc: one wave per doc
__global__ __launch_bounds__(64) void k_pool(
    const float* __restrict__ hfin, const float* __restrict__ w_gate,
    const float* __restrict__ b_gate, float* __restrict__ out) {
  int b = blockIdx.x, lane = threadIdx.x;
  float wg[NCLS];
#pragma unroll
  for (int c = 0; c < NCLS; ++c) wg[c] = w_gate[c];
  float bg = b_gate[0];
  float acc[NCLS];
#pragma unroll
  for (int c = 0; c < NCLS; ++c) acc[c] = 0.f;
  for (int n = lane; n < DLEN; n += 64) {
    const float* hr = hfin + ((size_t)b * DLEN + n) * NCLS;
    float hv[NCLS];
    float d = bg;
#pragma unroll
    for (int c = 0; c < NCLS; ++c) { hv[c] = hr[c]; d += hv[c] * wg[c]; }
    float g = 1.f / (1.f + expf(-d));
#pragma unroll
    for (int c = 0; c < NCLS; ++c) acc[c] += g * hv[c];
  }
#pragma unroll
  for (int off = 32; off > 0; off >>= 1) {
#pragma unroll
    for (int c = 0; c < NCLS; ++c) acc[c] += __shfl_down(acc[c], off);
  }
  if (lane == 0) {
#pragma unroll
    for (int c = 0; c < NCLS; ++c) out[b * NCLS + c] = acc[c];
  }
}

extern "C" void kernel_launch(void* const* d_in, const int* in_sizes, int n_in,
                              void* d_out, int out_size, void* d_ws, size_t ws_size,
                              hipStream_t stream) {
  const int* node_ids = (const int*)d_in[0];
  // d_in[1..3] (edge_src/edge_dst/graph_id) unused: band structure is static
  const float* emb    = (const float*)d_in[4];
  const float* W1     = (const float*)d_in[5];
  const float* b1     = (const float*)d_in[6];
  const float* W2     = (const float*)d_in[7];
  const float* b2     = (const float*)d_in[8];
  const float* gatW   = (const float*)d_in[9];
  const float* a_src  = (const float*)d_in[10];
  const float* a_dst  = (const float*)d_in[11];
  const float* w_gate = (const float*)d_in[12];
  const float* b_gate = (const float*)d_in[13];
  float* out = (float*)d_out;
  char* ws = (char*)d_ws;

  __bf16* W1T = (__bf16*)(ws + 0);        //   393,216 B
  float* hA  = (float*)(ws + 393216);     // 3,584,000 B
  float* hB  = (float*)(ws + 3977216);    // 3,584,000 B
  float* z   = (float*)(ws + 7561216);    // 28,672,000 B
  float* zt  = (float*)(ws + 36233216);   // 28,672,000 B
  float* att = (float*)(ws + 64905216);   // 11,468,800 B
  float* as_ = (float*)(ws + 76374016);   //  1,433,600 B
  float* ad_ = (float*)(ws + 77807616);   //  1,433,600 B  (total ~79.3 MB)

  k_transpose<<<768, 256, 0, stream>>>(W1, W1T);
  k_mlp<<<NB_NODES / 16, 256, 0, stream>>>(node_ids, emb, W1T, b1, W2, b2, hA);
  float* hin = hA;
  float* hout = hB;
  for (int l = 0; l < 2; ++l) {
    k_gat_pre<<<(NHEADS * NB_NODES) / 256, 256, 0, stream>>>(hin, gatW, a_src, a_dst, l, z, as_, ad_);
    k_att<<<(NHEADS * NB_NODES) / 256, 256, 0, stream>>>(as_, ad_, att);
    k_diffuse<<<NDOCS * NHEADS, 256, 0, stream>>>(z, att, zt);
    k_headmean<<<(NB_NODES * NCLS) / 256, 256, 0, stream>>>(zt, hout);
    float* tmp = hin; hin = hout; hout = tmp;
  }
  k_pool<<<NDOCS, 64, 0, stream>>>(hin, w_gate, b_gate, out);
}

// Round 3
// 438.059 us; speedup vs baseline: 1.3048x; 1.3048x over previous
//
#include <hip/hip_runtime.h>
#include <hip/hip_bf16.h>
#include <cstddef>

#define NB_NODES 44800   // B*L
#define NDOCS 128
#define DLEN 350
#define DIM 768
#define HID 256
#define NCLS 20
#define NHEADS 8

typedef __bf16 v8bf __attribute__((ext_vector_type(8)));
typedef __bf16 v4bf __attribute__((ext_vector_type(4)));
typedef float v4f __attribute__((ext_vector_type(4)));
using bf16 = __hip_bfloat16;

// ---- W1 [768,256] f32 -> W1T [256,768] bf16 so B-fragments are contiguous 16B loads
__global__ __launch_bounds__(256) void k_transpose(const float* __restrict__ W1,
                                                   __bf16* __restrict__ W1T) {
  int idx = blockIdx.x * 256 + threadIdx.x;   // idx = n*768 + k
  int n = idx / 768, k = idx - n * 768;
  W1T[idx] = (__bf16)W1[k * 256 + n];
}

// ---- fused gather + GEMM1(relu) + GEMM2 -> h0 [N,20] f32
// M=32 nodes/block, N=256. A staged ONCE into LDS in MFMA-fragment order
// (shared by all 4 waves), next K-chunk prefetched into regs across barrier.
__global__ __launch_bounds__(256) void k_mlp(
    const int* __restrict__ node_ids, const float* __restrict__ emb,
    const __bf16* __restrict__ W1T, const float* __restrict__ b1,
    const float* __restrict__ W2, const float* __restrict__ b2,
    float* __restrict__ h0) {
  __shared__ __bf16 As[2048];          // 4 KB: 4 frags x 64 lanes x 8 bf16
  __shared__ float xs[32 * 260];       // 33.3 KB (stride 260: float4-able, low conflict)
  __shared__ __bf16 w2s[HID * NCLS];   // 10 KB
  int tid = threadIdx.x;
  int wave = tid >> 6, lane = tid & 63;
  int quad = lane >> 4, l16 = lane & 15;
  int m0 = blockIdx.x * 32;

  // staging role: thread t supplies A[m=srow][k = k0 + skoff .. +8] to frag slot t*16B
  int srow = ((tid >> 7) & 1) * 16 + (tid & 15);           // msub*16 + l16
  int skoff = ((tid >> 6) & 1) * 32 + ((tid >> 4) & 3) * 8; // ksub*32 + quad*8
  int nid = node_ids[m0 + srow];
  const float* arow = emb + (size_t)nid * DIM + skoff;

  const __bf16* brow[4];
#pragma unroll
  for (int j = 0; j < 4; ++j)
    brow[j] = W1T + (size_t)(wave * 64 + j * 16 + l16) * DIM + quad * 8;

  v4f acc[2][4];
#pragma unroll
  for (int ms = 0; ms < 2; ++ms)
#pragma unroll
    for (int j = 0; j < 4; ++j) acc[ms][j] = (v4f){0.f, 0.f, 0.f, 0.f};

  v4f f0 = *(const v4f*)(arow);        // prefetch chunk 0
  v4f f1 = *(const v4f*)(arow + 4);

  for (int kc = 0; kc < 12; ++kc) {
    int k0 = kc * 64;
    __syncthreads();                   // prev chunk's A reads complete
    v8bf aw;
#pragma unroll
    for (int j = 0; j < 4; ++j) { aw[j] = (__bf16)f0[j]; aw[4 + j] = (__bf16)f1[j]; }
    *(v8bf*)(As + tid * 8) = aw;       // conflict-free b128 write
    __syncthreads();                   // staging visible
    int k1 = (kc + 1 < 12) ? (kc + 1) * 64 : 0;
    f0 = *(const v4f*)(arow + k1);     // prefetch next chunk (HBM latency overlaps MFMA)
    f1 = *(const v4f*)(arow + k1 + 4);

    v8bf af[2][2];
#pragma unroll
    for (int ms = 0; ms < 2; ++ms)
#pragma unroll
      for (int ks = 0; ks < 2; ++ks)
        af[ms][ks] = *(const v8bf*)(As + (ms * 2 + ks) * 512 + lane * 8);
#pragma unroll
    for (int ks = 0; ks < 2; ++ks) {
#pragma unroll
      for (int j = 0; j < 4; ++j) {
        v8bf b = *(const v8bf*)(brow[j] + k0 + ks * 32);
        acc[0][j] = __builtin_amdgcn_mfma_f32_16x16x32_bf16(af[0][ks], b, acc[0][j], 0, 0, 0);
        acc[1][j] = __builtin_amdgcn_mfma_f32_16x16x32_bf16(af[1][ks], b, acc[1][j], 0, 0, 0);
      }
    }
  }

  // epilogue: bias+relu into xs; stage W2 (bf16) into LDS
  for (int i = tid; i < HID * NCLS; i += 256) w2s[i] = (__bf16)W2[i];
#pragma unroll
  for (int ms = 0; ms < 2; ++ms)
#pragma unroll
    for (int j = 0; j < 4; ++j) {
      int n = wave * 64 + j * 16 + l16;
      float bb = b1[n];
#pragma unroll
      for (int r = 0; r < 4; ++r) {
        int m = ms * 16 + quad * 4 + r;       // C/D layout: col=l16, row=quad*4+r
        float v = acc[ms][j][r] + bb;
        xs[m * 260 + n] = v > 0.f ? v : 0.f;
      }
    }
  __syncthreads();

  // GEMM2: [32 x 256] @ [256 x 20] + b2 ; 160 threads, 4 cols each
  if (tid < 160) {
    int m = tid / 5, c0 = (tid % 5) * 4;
    float s0 = b2[c0], s1 = b2[c0 + 1], s2 = b2[c0 + 2], s3 = b2[c0 + 3];
    for (int k = 0; k < HID; ++k) {
      float x = xs[m * 260 + k];
      v4bf w = *(const v4bf*)(w2s + k * NCLS + c0);
      s0 += x * (float)w[0]; s1 += x * (float)w[1];
      s2 += x * (float)w[2]; s3 += x * (float)w[3];
    }
    *(v4f*)(h0 + (size_t)(m0 + m) * NCLS + c0) = (v4f){s0, s1, s2, s3};
  }
}

// ---- per (head, node): z = h @ W[l,h]. W in LDS, float4 I/O. h uniform per block.
__global__ __launch_bounds__(256) void k_gat_pre(
    const float* __restrict__ hin, const float* __restrict__ gatW, int layer,
    float* __restrict__ z) {
  __shared__ float Ws[NCLS * NCLS];
  int tid = threadIdx.x;
  int h = blockIdx.x / 175;                       // 175 blocks per head (175*256=44800)
  int n = (blockIdx.x % 175) * 256 + tid;
  const float* W = gatW + (size_t)(layer * NHEADS + h) * NCLS * NCLS;
  for (int i = tid; i < NCLS * NCLS; i += 256) Ws[i] = W[i];
  __syncthreads();
  float hi[NCLS];
  const v4f* h4 = (const v4f*)(hin + (size_t)n * NCLS);
#pragma unroll
  for (int q = 0; q < 5; ++q) {
    v4f t = h4[q];
#pragma unroll
    for (int j = 0; j < 4; ++j) hi[q * 4 + j] = t[j];
  }
  v4f* z4 = (v4f*)(z + ((size_t)h * NB_NODES + n) * NCLS);
#pragma unroll
  for (int q = 0; q < 5; ++q) {
    v4f o;
#pragma unroll
    for (int j = 0; j < 4; ++j) {
      int d = q * 4 + j;
      float s = 0.f;
#pragma unroll
      for (int c = 0; c < NCLS; ++c) s += hi[c] * Ws[c * NCLS + d];
      o[j] = s;
    }
    z4[q] = o;
  }
}

// ---- fused: banded edge-softmax + K=3 diffusion + elu, per (doc, head)
__global__ __launch_bounds__(256) void k_diffuse(
    const float* __restrict__ z, const float* __restrict__ a_src,
    const float* __restrict__ a_dst, int layer, float* __restrict__ eluzt) {
  __shared__ float zts[DLEN * NCLS];   // 28 KB
  __shared__ float attsh[DLEN * 7];    // 9.8 KB
  __shared__ float asv[DLEN], adv[DLEN];
  __shared__ float avec[NCLS], dvec[NCLS];
  int tid = threadIdx.x;
  int h = blockIdx.x & 7;
  int doc = blockIdx.x >> 3;
  size_t baseN = (size_t)h * NB_NODES + (size_t)doc * DLEN;
  const float* zg = z + baseN * NCLS;
  for (int i = tid; i < DLEN * NCLS / 4; i += 256)
    ((v4f*)zts)[i] = ((const v4f*)zg)[i];
  if (tid < NCLS) {
    avec[tid] = a_src[(layer * NHEADS + h) * NCLS + tid];
    dvec[tid] = a_dst[(layer * NHEADS + h) * NCLS + tid];
  }
  __syncthreads();

  float z0r[28];
#pragma unroll
  for (int i = 0; i < 28; ++i) {
    int idx = tid + i * 256;
    if (idx < DLEN * NCLS) z0r[i] = zts[idx];
  }
  // alpha_src / alpha_dst per node
  for (int n = tid; n < DLEN; n += 256) {
    float sa = 0.f, sd = 0.f;
    for (int d = 0; d < NCLS; ++d) {
      float v = zts[n * NCLS + d];
      sa += v * avec[d]; sd += v * dvec[d];
    }
    asv[n] = sa; adv[n] = sd;
  }
  __syncthreads();
  // banded softmax over incoming edges at each node
  for (int n = tid; n < DLEN; n += 256) {
    float ad = adv[n];
    float e[7]; float m = -1e30f;
#pragma unroll
    for (int j = 0; j < 7; ++j) {
      int s = n - 3 + j;
      bool valid = (s >= 0) && (s < DLEN);
      float x = valid ? asv[s] + ad : -1e30f;
      x = x > 0.f ? x : 0.2f * x;
      e[j] = valid ? x : -1e30f;
      if (e[j] > m) m = e[j];
    }
    float sum = 0.f;
#pragma unroll
    for (int j = 0; j < 7; ++j) {
      float ex = (e[j] > -1e29f) ? expf(e[j] - m) : 0.f;
      e[j] = ex; sum += ex;
    }
    float inv = 1.f / (sum + 1e-9f);
#pragma unroll
    for (int j = 0; j < 7; ++j) attsh[n * 7 + j] = e[j] * inv;
  }
  __syncthreads();

  float vr[28];
  for (int t = 0; t < 3; ++t) {
#pragma unroll
    for (int i = 0; i < 28; ++i) {
      int idx = tid + i * 256;
      if (idx < DLEN * NCLS) {
        int n = idx / NCLS, c = idx - n * NCLS;
        float agg = 0.f;
#pragma unroll
        for (int j = 0; j < 7; ++j) {
          int s = n - 3 + j;
          s = s < 0 ? 0 : (s > DLEN - 1 ? DLEN - 1 : s);  // invalid slots have att 0
          agg += attsh[n * 7 + j] * zts[s * NCLS + c];
        }
        vr[i] = 0.85f * agg + 0.15f * z0r[i];
      }
    }
    __syncthreads();
#pragma unroll
    for (int i = 0; i < 28; ++i) {
      int idx = tid + i * 256;
      if (idx < DLEN * NCLS) zts[idx] = vr[i];
    }
    __syncthreads();
  }
  float* og = eluzt + baseN * NCLS;
#pragma unroll
  for (int i = 0; i < 28; ++i) {
    int idx = tid + i * 256;
    if (idx < DLEN * NCLS) {
      float x = vr[i];
      og[idx] = x > 0.f ? x : expf(x) - 1.f;   // elu (coalesced dword stores)
    }
  }
}

// ---- mean over heads, float4
__global__ __launch_bounds__(256) void k_headmean(
    const float* __restrict__ eluzt, float* __restrict__ hout) {
  int idx = blockIdx.x * 256 + threadIdx.x;   // < N*20/4 = 224000
  v4f s = (v4f){0.f, 0.f, 0.f, 0.f};
#pragma unroll
  for (int h = 0; h < NHEADS; ++h)
    s += ((const v4f*)eluzt)[(size_t)h * (NB_NODES * NCLS / 4) + idx];
  v4f o; o[0] = s[0] * 0.125f; o[1] = s[1] * 0.125f; o[2] = s[2] * 0.125f; o[3] = s[3] * 0.125f;
  ((v4f*)hout)[idx] = o;
}

// ---- gated pooling per doc: one wave per doc
__global__ __launch_bounds__(64) void k_pool(
    const float* __restrict__ hfin, const float* __restrict__ w_gate,
    const float* __restrict__ b_gate, float* __restrict__ out) {
  int b = blockIdx.x, lane = threadIdx.x;
  float wg[NCLS];
#pragma unroll
  for (int c = 0; c < NCLS; ++c) wg[c] = w_gate[c];
  float bg = b_gate[0];
  float acc[NCLS];
#pragma unroll
  for (int c = 0; c < NCLS; ++c) acc[c] = 0.f;
  for (int n = lane; n < DLEN; n += 64) {
    const v4f* hr = (const v4f*)(hfin + ((size_t)b * DLEN + n) * NCLS);
    float hv[NCLS];
    float d = bg;
#pragma unroll
    for (int q = 0; q < 5; ++q) {
      v4f t = hr[q];
#pragma unroll
      for (int j = 0; j < 4; ++j) { hv[q * 4 + j] = t[j]; d += t[j] * wg[q * 4 + j]; }
    }
    float g = 1.f / (1.f + expf(-d));
#pragma unroll
    for (int c = 0; c < NCLS; ++c) acc[c] += g * hv[c];
  }
#pragma unroll
  for (int off = 32; off > 0; off >>= 1) {
#pragma unroll
    for (int c = 0; c < NCLS; ++c) acc[c] += __shfl_down(acc[c], off);
  }
  if (lane == 0) {
#pragma unroll
    for (int c = 0; c < NCLS; ++c) out[b * NCLS + c] = acc[c];
  }
}

extern "C" void kernel_launch(void* const* d_in, const int* in_sizes, int n_in,
                              void* d_out, int out_size, void* d_ws, size_t ws_size,
                              hipStream_t stream) {
  const int* node_ids = (const int*)d_in[0];
  // d_in[1..3] (edge_src/edge_dst/graph_id) unused: band structure is static
  const float* emb    = (const float*)d_in[4];
  const float* W1     = (const float*)d_in[5];
  const float* b1     = (const float*)d_in[6];
  const float* W2     = (const float*)d_in[7];
  const float* b2     = (const float*)d_in[8];
  const float* gatW   = (const float*)d_in[9];
  const float* a_src  = (const float*)d_in[10];
  const float* a_dst  = (const float*)d_in[11];
  const float* w_gate = (const float*)d_in[12];
  const float* b_gate = (const float*)d_in[13];
  float* out = (float*)d_out;
  char* ws = (char*)d_ws;

  __bf16* W1T = (__bf16*)(ws + 0);        //   393,216 B
  float* hA  = (float*)(ws + 393216);     // 3,584,000 B
  float* hB  = (float*)(ws + 3977216);    // 3,584,000 B
  float* z   = (float*)(ws + 7561216);    // 28,672,000 B
  float* zt  = (float*)(ws + 36233216);   // 28,672,000 B (total ~64.9 MB)

  k_transpose<<<768, 256, 0, stream>>>(W1, W1T);
  k_mlp<<<NB_NODES / 32, 256, 0, stream>>>(node_ids, emb, W1T, b1, W2, b2, hA);
  float* hin = hA;
  float* hout = hB;
  for (int l = 0; l < 2; ++l) {
    k_gat_pre<<<(NHEADS * NB_NODES) / 256, 256, 0, stream>>>(hin, gatW, l, z);
    k_diffuse<<<NDOCS * NHEADS, 256, 0, stream>>>(z, a_src, a_dst, l, zt);
    k_headmean<<<(NB_NODES * NCLS / 4) / 256, 256, 0, stream>>>(zt, hout);
    float* tmp = hin; hin = hout; hout = tmp;
  }
  k_pool<<<NDOCS, 64, 0, stream>>>(hin, w_gate, b_gate, out);
}